// Round 1
// baseline (673.503 us; speedup 1.0000x reference)
//
#include <hip/hip_runtime.h>
#include <math.h>

#define NN 40000
#define FF 256
#define DD 64
#define LHH 200
#define BB 512
#define TDD 16
#define GE_HASH 1024

// freqs[j] = 10^(-0.3125*j)  (TGAT-style log-spaced, TD=16, span 5 decades)
__constant__ float TFREQ[16] = {
    1.0f,            0.48696753f,    0.23713737f,    0.115478195f,
    0.056234132f,    0.027384196f,   0.013335215f,   0.0064938162f,
    0.0031622776f,   0.0015399265f,  0.00074989421f, 0.00036517414f,
    0.00017782794f,  8.6596433e-05f, 4.2169650e-05f, 2.0535251e-05f
};

// ---------------------------------------------------------------------------
// K1: C[n][0:64] = sum_k A[n][k] * W[m][k] + bias[m]   (W row-major (64,KDIM))
// block 256 threads computes 128 rows x 64 cols; k staged in chunks of 8.
// ---------------------------------------------------------------------------
template<int KDIM>
__global__ void __launch_bounds__(256)
gemm_nt_kernel(const float* __restrict__ A, const float* __restrict__ W,
               const float* __restrict__ bias, float* __restrict__ C, int Nrows)
{
    __shared__ __align__(16) float a_t[128][8];
    __shared__ __align__(16) float wt[8][64];
    const int tid = threadIdx.x;
    const int tx = tid & 15;        // dims 4*tx .. 4*tx+3
    const int ty = tid >> 4;        // row lane 0..15 ; rows ty + 16*rr
    const int n0 = blockIdx.x * 128;

    float4 acc[8];
#pragma unroll
    for (int r = 0; r < 8; ++r) acc[r] = make_float4(0.f, 0.f, 0.f, 0.f);

    for (int kc = 0; kc < KDIM; kc += 8) {
        __syncthreads();
        {   // stage A tile (128 x 8)
            int r = tid >> 1;
            int cc = (tid & 1) * 4;
            int n = n0 + r;
            float4 v = make_float4(0.f, 0.f, 0.f, 0.f);
            if (n < Nrows) v = *(const float4*)(A + (size_t)n * KDIM + kc + cc);
            *(float4*)&a_t[r][cc] = v;
        }
        {   // stage W tile transposed: wt[f][m] = W[m][kc+f]
            int m = tid >> 2;
            int f0 = (tid & 3) * 2;
            float2 v = *(const float2*)(W + (size_t)m * KDIM + kc + f0);
            wt[f0][m] = v.x; wt[f0 + 1][m] = v.y;
        }
        __syncthreads();
        float4 w4[8];
#pragma unroll
        for (int f = 0; f < 8; ++f) w4[f] = *(float4*)&wt[f][tx * 4];
#pragma unroll
        for (int rr = 0; rr < 8; ++rr) {
            int row = ty + rr * 16;
            float4 a0 = *(float4*)&a_t[row][0];
            float4 a1 = *(float4*)&a_t[row][4];
            float av[8] = {a0.x, a0.y, a0.z, a0.w, a1.x, a1.y, a1.z, a1.w};
#pragma unroll
            for (int f = 0; f < 8; ++f) {
                acc[rr].x += av[f] * w4[f].x;
                acc[rr].y += av[f] * w4[f].y;
                acc[rr].z += av[f] * w4[f].z;
                acc[rr].w += av[f] * w4[f].w;
            }
        }
    }
    float4 bv = make_float4(0.f, 0.f, 0.f, 0.f);
    if (bias) bv = *(const float4*)(bias + tx * 4);
#pragma unroll
    for (int rr = 0; rr < 8; ++rr) {
        int n = n0 + ty + rr * 16;
        if (n < Nrows) {
            float4 o = acc[rr];
            o.x += bv.x; o.y += bv.y; o.z += bv.z; o.w += bv.w;
            *(float4*)(C + (size_t)n * DD + tx * 4) = o;
        }
    }
}

// ---------------------------------------------------------------------------
// K2: fused dygkt encoder + GRU scan. One block (192 thr = 3 waves) / sequence.
// Thread j owns gate row j: Wih[j,:] and Whh[j,:] live in 128 VGPRs.
// ---------------------------------------------------------------------------
__global__ void __launch_bounds__(192)
seq_gru_kernel(const int* __restrict__ nids_all, const int* __restrict__ eids_all,
               const float* __restrict__ times_all, const int* __restrict__ cur_ids,
               const float* __restrict__ node_raw, const float* __restrict__ edge_raw,
               const float* __restrict__ proj_node,
               const float* __restrict__ Wedge, const float* __restrict__ bedge,
               const float* __restrict__ Wtime, const float* __restrict__ btime,
               const float* __restrict__ Wstruct, const float* __restrict__ bstruct,
               const float* __restrict__ ln_g, const float* __restrict__ ln_b,
               const float* __restrict__ Wih, const float* __restrict__ Whh,
               const float* __restrict__ bih, const float* __restrict__ bhh,
               float* __restrict__ emb_out)
{
    __shared__ __align__(16) float xbuf[LHH][DD];     // 51200 B
    __shared__ __align__(16) float cbuf[LHH][TDD];    // 12800 B
    __shared__ float wtimeT[TDD][DD];                 // 4096 B
    __shared__ float wedge_s[DD], cbias_s[DD], ws_s[DD], lng_s[DD], lnb_s[DD];
    __shared__ __align__(16) float hbuf[DD];
    __shared__ float rbuf[DD], zbuf[DD];

    const int b = blockIdx.x;
    const int tid = threadIdx.x;
    const int lane = tid & 63;
    const int w = tid >> 6;

    if (tid < DD) {
        wedge_s[tid] = Wedge[tid];
        cbias_s[tid] = bedge[tid] + btime[tid] + 2.0f * bstruct[tid];
        ws_s[tid]    = Wstruct[tid];
        lng_s[tid]   = ln_g[tid];
        lnb_s[tid]   = ln_b[tid];
        hbuf[tid]    = 0.f;
    }
    for (int i = tid; i < DD * TDD; i += 192) {
        // wtimeT[j][d] = Wtime[d*16 + j] ; i == d*16+j
        wtimeT[i & 15][i >> 4] = Wtime[i];
    }
    // cos table: cbuf[l][j] = cos(t_l * freq_j)
    for (int i = tid; i < LHH * TDD; i += 192) {
        int l = i >> 4, j = i & 15;
        float t = times_all[b * LHH + l];
        cbuf[l][j] = cosf(t * TFREQ[j]);
    }

    // per-thread GRU weight rows (kept in registers via full unroll)
    float wih[DD], whh[DD];
    {
        const float* wi = Wih + (size_t)tid * DD;
        const float* wh = Whh + (size_t)tid * DD;
#pragma unroll
        for (int k4 = 0; k4 < 16; ++k4) {
            float4 a = *(const float4*)(wi + k4 * 4);
            wih[k4 * 4 + 0] = a.x; wih[k4 * 4 + 1] = a.y;
            wih[k4 * 4 + 2] = a.z; wih[k4 * 4 + 3] = a.w;
            float4 h4 = *(const float4*)(wh + k4 * 4);
            whh[k4 * 4 + 0] = h4.x; whh[k4 * 4 + 1] = h4.y;
            whh[k4 * 4 + 2] = h4.z; whh[k4 * 4 + 3] = h4.w;
        }
    }
    const float bi = bih[tid];
    const float bh = bhh[tid];
    const int cur = cur_ids[b];
    const int cur_skill = (int)node_raw[(size_t)cur * FF];
    __syncthreads();

    // ---- phase 1: encode all 200 elements (wave w does l = w, w+3, ...)
    for (int l = w; l < LHH; l += 3) {
        int nid = nids_all[b * LHH + l];
        int eid = eids_all[b * LHH + l];
        float pv = proj_node[(size_t)nid * DD + lane];        // has bfeat folded in
        float e0 = edge_raw[(size_t)eid * 4];
        float co = (nid == cur) ? 1.f : 0.f;
        float sim = (((int)node_raw[(size_t)nid * FF]) == cur_skill) ? 1.f : 0.f;
        float tf = 0.f;
#pragma unroll
        for (int j = 0; j < TDD; ++j) tf += cbuf[l][j] * wtimeT[j][lane];
        float v = pv + e0 * wedge_s[lane] + tf + (co + sim) * ws_s[lane] + cbias_s[lane];
        // LayerNorm across the 64 lanes
        float m = v;
#pragma unroll
        for (int off = 32; off > 0; off >>= 1) m += __shfl_xor(m, off);
        m *= (1.f / 64.f);
        float dv = v - m;
        float var = dv * dv;
#pragma unroll
        for (int off = 32; off > 0; off >>= 1) var += __shfl_xor(var, off);
        var *= (1.f / 64.f);
        xbuf[l][lane] = dv * rsqrtf(var + 1e-5f) * lng_s[lane] + lnb_s[lane];
    }
    __syncthreads();

    // ---- phase 2: sequential GRU (gate order r,z,n)
    for (int l = 0; l < LHH; ++l) {
        float4 gia = make_float4(0.f, 0.f, 0.f, 0.f);
        float4 gha = make_float4(0.f, 0.f, 0.f, 0.f);
        const float4* xv4 = (const float4*)&xbuf[l][0];
        const float4* hv4 = (const float4*)&hbuf[0];
#pragma unroll
        for (int kk = 0; kk < 16; ++kk) {
            float4 xv = xv4[kk];
            float4 hv = hv4[kk];
            gia.x += wih[kk * 4 + 0] * xv.x; gia.y += wih[kk * 4 + 1] * xv.y;
            gia.z += wih[kk * 4 + 2] * xv.z; gia.w += wih[kk * 4 + 3] * xv.w;
            gha.x += whh[kk * 4 + 0] * hv.x; gha.y += whh[kk * 4 + 1] * hv.y;
            gha.z += whh[kk * 4 + 2] * hv.z; gha.w += whh[kk * 4 + 3] * hv.w;
        }
        float gi = bi + ((gia.x + gia.y) + (gia.z + gia.w));
        float gh = bh + ((gha.x + gha.y) + (gha.z + gha.w));
        if (tid < 128) {    // r and z gates
            float s = 1.f / (1.f + expf(-(gi + gh)));
            if (tid < 64) rbuf[tid] = s; else zbuf[tid - 64] = s;
        }
        __syncthreads();
        if (tid >= 128) {   // n gate + h update
            int k = tid - 128;
            float n = tanhf(gi + rbuf[k] * gh);
            float z = zbuf[k];
            hbuf[k] = (1.f - z) * n + z * hbuf[k];
        }
        __syncthreads();
    }
    if (tid >= 128) emb_out[(size_t)b * DD + (tid - 128)] = hbuf[tid - 128];
}

// ---------------------------------------------------------------------------
// K3: graph_emb — hash-dedup'd GCNConv + mean pool. One block per batch row.
// ---------------------------------------------------------------------------
__device__ __forceinline__ int hlookup(const unsigned* hkey, const int* hslot, unsigned id)
{
    unsigned p = (id * 2654435761u) & (GE_HASH - 1);
    while (hkey[p] != id) p = (p + 1) & (GE_HASH - 1);
    return hslot[p];
}

__global__ void __launch_bounds__(256)
graph_emb_kernel(const int* __restrict__ retrieved, const int* __restrict__ pool_nodes,
                 const float* __restrict__ hgcn, const float* __restrict__ gcn_b,
                 float* __restrict__ glob)
{
    __shared__ float agg[400 * 64];          // 102400 B
    __shared__ unsigned hkey[GE_HASH];
    __shared__ int hslot[GE_HASH];
    __shared__ unsigned ekey[GE_HASH];
    __shared__ int slot_id[400];
    __shared__ unsigned deg[400];
    __shared__ float dis[400];
    __shared__ unsigned elist[400];
    __shared__ int ids[400];
    __shared__ int pids[8];
    __shared__ int cntU, cntE;
    __shared__ float gcnb_s[64];
    __shared__ float red[4][64];

    const int b = blockIdx.x;
    const int tid = threadIdx.x;
    const int lane = tid & 63, wid = tid >> 6;

    if (tid < 8)  pids[tid] = retrieved[b * 8 + tid];
    if (tid < 64) gcnb_s[tid] = gcn_b[tid];
    if (tid == 0) { cntU = 0; cntE = 0; }
    for (int i = tid; i < GE_HASH; i += 256) { hkey[i] = 0u; ekey[i] = 0u; }
    for (int i = tid; i < 400; i += 256) deg[i] = 0u;
    __syncthreads();

    for (int i = tid; i < 400; i += 256) {
        int k = i / 50, p = i % 50;
        ids[i] = pool_nodes[(size_t)pids[k] * 50 + p];
    }
    __syncthreads();

    // node dedup
    for (int i = tid; i < 400; i += 256) {
        int idi = ids[i];
        if (idi > 0) {
            unsigned id = (unsigned)idi;
            unsigned p = (id * 2654435761u) & (GE_HASH - 1);
            while (true) {
                unsigned old = atomicCAS(&hkey[p], 0u, id);
                if (old == 0u) {
                    int s = atomicAdd(&cntU, 1);
                    hslot[p] = s; slot_id[s] = idi;
                    break;
                }
                if (old == id) break;
                p = (p + 1) & (GE_HASH - 1);
            }
        }
    }
    __syncthreads();

    // consecutive-pair edges, dedup by key = min*N + max (fits uint32)
    for (int i = tid; i < 8 * 49; i += 256) {
        int k = i / 49, p = i % 49;
        int u = ids[k * 50 + p], v = ids[k * 50 + p + 1];
        if (u > 0 && v > 0) {
            unsigned a = (unsigned)min(u, v), bb = (unsigned)max(u, v);
            unsigned key = a * 40000u + bb;
            unsigned p2 = (key * 2654435761u) & (GE_HASH - 1);
            while (true) {
                unsigned old = atomicCAS(&ekey[p2], 0u, key);
                if (old == 0u) {    // first occurrence -> unique edge
                    int su = hlookup(hkey, hslot, a);
                    int sv = hlookup(hkey, hslot, bb);
                    int e = atomicAdd(&cntE, 1);
                    elist[e] = ((unsigned)su << 16) | (unsigned)sv;
                    atomicAdd(&deg[su], 1u);
                    atomicAdd(&deg[sv], 1u);
                    break;
                }
                if (old == key) break;
                p2 = (p2 + 1) & (GE_HASH - 1);
            }
        }
    }
    __syncthreads();

    const int U = cntU, EC = cntE;
    for (int s = tid; s < U; s += 256) dis[s] = rsqrtf((float)deg[s] + 1.0f); // +1 self loop
    __syncthreads();

    // init agg rows: gcn_b + dis^2 * h_self
    for (int s = wid; s < U; s += 4) {
        float d2 = dis[s] * dis[s];
        float hval = hgcn[(size_t)slot_id[s] * 64 + lane];
        agg[s * 64 + lane] = gcnb_s[lane] + d2 * hval;
    }
    __syncthreads();

    // edge contributions (sym-norm)
    for (int e = wid; e < EC; e += 4) {
        unsigned pk = elist[e];
        int su = (int)(pk >> 16), sv = (int)(pk & 0xffffu);
        float nrm = dis[su] * dis[sv];
        float hu = hgcn[(size_t)slot_id[su] * 64 + lane];
        float hv = hgcn[(size_t)slot_id[sv] * 64 + lane];
        atomicAdd(&agg[sv * 64 + lane], nrm * hu);
        atomicAdd(&agg[su * 64 + lane], nrm * hv);
    }
    __syncthreads();

    // relu + mean over unique nodes
    float acc = 0.f;
    for (int s = wid; s < U; s += 4) acc += fmaxf(agg[s * 64 + lane], 0.f);
    red[wid][lane] = acc;
    __syncthreads();
    if (tid < 64) {
        float tot = red[0][tid] + red[1][tid] + red[2][tid] + red[3][tid];
        glob[(size_t)b * 64 + tid] = tot / (float)max(U, 1);
    }
}

// ---------------------------------------------------------------------------
// K4: fusion + output heads. One wave per batch row.
// ---------------------------------------------------------------------------
__global__ void __launch_bounds__(64)
head_kernel(const float* __restrict__ local_emb, const float* __restrict__ glob,
            const float* __restrict__ q_emb,
            const float* __restrict__ fus_W, const float* __restrict__ fus_b,
            const float* __restrict__ out_W, const float* __restrict__ out_b,
            float* __restrict__ out)
{
    __shared__ float cat[128];
    __shared__ float fus[64];
    __shared__ float qv[64];
    const int b = blockIdx.x, d = threadIdx.x;
    cat[d]      = local_emb[(size_t)b * 64 + d];
    cat[64 + d] = glob[(size_t)b * 64 + d];
    qv[d]       = q_emb[(size_t)b * 64 + d];
    __syncthreads();
    float acc = fus_b[d];
    const float* fw = fus_W + (size_t)d * 128;
#pragma unroll 4
    for (int k = 0; k < 128; ++k) acc += cat[k] * fw[k];
    fus[d] = fmaxf(acc, 0.f);
    __syncthreads();
    float o0 = out_b[d], o1 = out_b[d];
    const float* ow = out_W + (size_t)d * 64;
#pragma unroll 4
    for (int k = 0; k < 64; ++k) { float ww = ow[k]; o0 += fus[k] * ww; o1 += qv[k] * ww; }
    out[(size_t)b * 64 + d] = o0;
    out[(size_t)BB * 64 + (size_t)b * 64 + d] = o1;
}

// ---------------------------------------------------------------------------
extern "C" void kernel_launch(void* const* d_in, const int* in_sizes, int n_in,
                              void* d_out, int out_size, void* d_ws, size_t ws_size,
                              hipStream_t stream)
{
    const int*   src_ids    = (const int*)d_in[0];
    const int*   dst_ids    = (const int*)d_in[1];
    const int*   l_nids     = (const int*)d_in[2];
    const int*   l_eids     = (const int*)d_in[3];
    const float* l_times    = (const float*)d_in[4];
    const int*   d_nids     = (const int*)d_in[5];
    const int*   d_eids     = (const int*)d_in[6];
    const float* d_times    = (const float*)d_in[7];
    const int*   retr       = (const int*)d_in[8];
    const float* node_raw   = (const float*)d_in[9];
    const float* edge_raw   = (const float*)d_in[10];
    const int*   pool_nodes = (const int*)d_in[11];
    const float* Wfeat  = (const float*)d_in[12];
    const float* bfeat  = (const float*)d_in[13];
    const float* Wedge  = (const float*)d_in[14];
    const float* bedge  = (const float*)d_in[15];
    const float* Wtime  = (const float*)d_in[16];
    const float* btime  = (const float*)d_in[17];
    const float* Wstruct= (const float*)d_in[18];
    const float* bstruct= (const float*)d_in[19];
    const float* ln_g   = (const float*)d_in[20];
    const float* ln_b   = (const float*)d_in[21];
    const float* gruL_Wih = (const float*)d_in[22];
    const float* gruL_Whh = (const float*)d_in[23];
    const float* gruL_bih = (const float*)d_in[24];
    const float* gruL_bhh = (const float*)d_in[25];
    const float* gruQ_Wih = (const float*)d_in[26];
    const float* gruQ_Whh = (const float*)d_in[27];
    const float* gruQ_bih = (const float*)d_in[28];
    const float* gruQ_bhh = (const float*)d_in[29];
    const float* gcn_W  = (const float*)d_in[30];
    const float* gcn_b  = (const float*)d_in[31];
    const float* fus_W  = (const float*)d_in[32];
    const float* fus_b  = (const float*)d_in[33];
    const float* out_W  = (const float*)d_in[34];
    const float* out_b  = (const float*)d_in[35];

    float* ws        = (float*)d_ws;
    float* proj_node = ws;                                   // N*64 f32
    float* hgcn      = proj_node + (size_t)NN * DD;          // N*64
    float* local_emb = hgcn + (size_t)NN * DD;               // B*64
    float* q_emb     = local_emb + (size_t)BB * DD;          // B*64
    float* glob      = q_emb + (size_t)BB * DD;              // B*64

    dim3 g1((NN + 127) / 128);
    gemm_nt_kernel<FF><<<g1, 256, 0, stream>>>(node_raw, Wfeat, bfeat, proj_node, NN);
    gemm_nt_kernel<DD><<<g1, 256, 0, stream>>>(proj_node, gcn_W, nullptr, hgcn, NN);

    seq_gru_kernel<<<BB, 192, 0, stream>>>(l_nids, l_eids, l_times, dst_ids,
        node_raw, edge_raw, proj_node, Wedge, bedge, Wtime, btime, Wstruct, bstruct,
        ln_g, ln_b, gruL_Wih, gruL_Whh, gruL_bih, gruL_bhh, local_emb);
    seq_gru_kernel<<<BB, 192, 0, stream>>>(d_nids, d_eids, d_times, src_ids,
        node_raw, edge_raw, proj_node, Wedge, bedge, Wtime, btime, Wstruct, bstruct,
        ln_g, ln_b, gruQ_Wih, gruQ_Whh, gruQ_bih, gruQ_bhh, q_emb);

    graph_emb_kernel<<<BB, 256, 0, stream>>>(retr, pool_nodes, hgcn, gcn_b, glob);

    head_kernel<<<BB, 64, 0, stream>>>(local_emb, glob, q_emb,
        fus_W, fus_b, out_W, out_b, (float*)d_out);
}